// Round 2
// baseline (5114.163 us; speedup 1.0000x reference)
//
#include <hip/hip_runtime.h>
#include <cstdint>

#define NBATCH 128
#define NT 512
#define NT1 513
#define NS 64
#define NU 512
#define NBW 16   // batches per workgroup (MFMA M-tile)

typedef __attribute__((ext_vector_type(8))) short short8_t;
typedef __attribute__((ext_vector_type(4))) float f32x4;

__device__ __forceinline__ float sigf(float z) {
    return 1.0f / (1.0f + __expf(-z));
}
__device__ __forceinline__ float tanh_fast(float z) {
    return 2.0f / (1.0f + __expf(-2.0f * z)) - 1.0f;
}
// round-to-nearest-even f32 -> bf16, result in TOP 16 bits
__device__ __forceinline__ uint32_t bf16_top(float f) {
    uint32_t u = __float_as_uint(f);
    u += 0x7FFFu + ((u >> 16) & 1u);
    return u & 0xFFFF0000u;
}
__device__ __forceinline__ float f_from_lo(uint32_t p) { return __uint_as_float(p << 16); }
__device__ __forceinline__ float f_from_hi(uint32_t p) { return __uint_as_float(p & 0xFFFF0000u); }

// ---------------------------------------------------------------------------
// Kernel A: feedforward gates for all (b,t): ci = tanh(x@W_ci + b_ci),
// og = sigmoid(x@W_og + b_og). One-hot action => single extra weight row.
// Stores packed bf16 (ci low 16, og high 16) into ws.  (unchanged, validated)
// ---------------------------------------------------------------------------
__global__ __launch_bounds__(512) void ff_kernel(
    const float* __restrict__ states, const int* __restrict__ actions,
    const float* __restrict__ W_ci, const float* __restrict__ b_ci,
    const float* __restrict__ W_og, const float* __restrict__ b_og,
    uint32_t* __restrict__ ciog)
{
    __shared__ __align__(16) float sh_s[32][64];
    __shared__ int sh_a[32];
    const int tid = threadIdx.x;
    const int b = blockIdx.x / 17;
    const int t0 = (blockIdx.x % 17) * 32;
    const int tcnt = (t0 + 32 <= NT1) ? 32 : (NT1 - t0);

    const float* sp = states + ((size_t)b * NT1 + t0) * NS;
    for (int j = tid; j < tcnt * 16; j += 512) {
        const float4 v = *(const float4*)(sp + j * 4);
        *(float4*)&sh_s[j >> 4][(j & 15) * 4] = v;
    }
    for (int tt = tid; tt < tcnt; tt += 512) {
        const int t = t0 + tt;
        sh_a[tt] = (t < NT) ? actions[b * NT + t] : -1;
    }
    __syncthreads();

    const int u = tid;
    float accc[32], acco[32];
    const float bc = b_ci[u], bo = b_og[u];
    #pragma unroll
    for (int tt = 0; tt < 32; ++tt) { accc[tt] = bc; acco[tt] = bo; }

    for (int i = 0; i < NS; ++i) {
        const float wc = W_ci[(size_t)i * NU + u];
        const float wo = W_og[(size_t)i * NU + u];
        #pragma unroll
        for (int tt = 0; tt < 32; ++tt) {
            const float s = sh_s[tt][i];
            accc[tt] = fmaf(s, wc, accc[tt]);
            acco[tt] = fmaf(s, wo, acco[tt]);
        }
    }
    #pragma unroll
    for (int tt = 0; tt < 32; ++tt) {
        if (tt < tcnt) {
            float zc = accc[tt], zo = acco[tt];
            const int a = sh_a[tt];
            if (a >= 0) {
                zc += W_ci[(size_t)(NS + a) * NU + u];
                zo += W_og[(size_t)(NS + a) * NU + u];
            }
            const float ci = tanh_fast(zc);
            const float og = sigf(zo);
            ciog[((size_t)b * NT1 + t0 + tt) * NU + u] = bf16_top(og) | (bf16_top(ci) >> 16);
        }
    }
}

// ---------------------------------------------------------------------------
// Kernel B (new): MFMA recurrence with W_ig resident in VGPRs.
// 8 WGs x 512 threads; WG owns 16 batches. 8 waves each own a 64-wide u-slice.
// Per wave: B-operand = W_ig slice as 16 kf x 4 nf bf16 fragments (256 VGPRs,
// loaded once). Per step: A-operand = h (16x512 bf16) read from LDS
// (XOR-swizzled rows to avoid the 1024B-stride 16-way bank conflict),
// 64 MFMAs accumulate z = h @ W_ig, then per-lane gate math updates the
// persistent cell state c (16 f32/lane) and writes h_{t+1} (bf16, swizzled)
// into the other LDS buffer. ci/og prefetched from ws at loop top.
// One barrier per step (h and ysum are double-buffered).
// ---------------------------------------------------------------------------
__global__ __launch_bounds__(512, 2) void rec_mfma(
    const float* __restrict__ W_ig, const float* __restrict__ b_ig,
    const float* __restrict__ W_lin, const float* __restrict__ b_lin,
    const uint32_t* __restrict__ ciog, float* __restrict__ out)
{
    __shared__ short hsh[2][NBW * NU];      // 2 x 16KB, row stride 1024B
    __shared__ float ysum[2][8][NBW];

    const int tid  = threadIdx.x;
    const int lane = tid & 63;
    const int wv   = tid >> 6;      // wave 0..7, owns u in [wv*64, wv*64+64)
    const int n0   = wv << 6;
    const int r16  = lane & 15;     // A row (batch) / B col (u within frag)
    const int kg   = lane >> 4;     // k-group 0..3
    const int b0   = blockIdx.x * NBW;

    // ---- one-time: W_ig bf16 fragments into registers (256 VGPRs) ----
    short8_t wfrag[16][4];
    #pragma unroll
    for (int kf = 0; kf < 16; ++kf) {
        #pragma unroll
        for (int nf = 0; nf < 4; ++nf) {
            const int u  = n0 + nf * 16 + r16;
            const int kb = kf * 32 + kg * 8;
            short8_t w;
            #pragma unroll
            for (int j = 0; j < 8; ++j) {
                w[j] = (short)(bf16_top(W_ig[(size_t)(kb + j) * NU + u]) >> 16);
            }
            wfrag[kf][nf] = w;
        }
    }

    float big[4], wl[4];
    #pragma unroll
    for (int nf = 0; nf < 4; ++nf) {
        big[nf] = b_ig[n0 + nf * 16 + r16];
        wl[nf]  = W_lin[n0 + nf * 16 + r16];
    }
    const float blin = b_lin[0];

    // zero h buffer 0
    for (int i = tid; i < NBW * NU; i += 512) hsh[0][i] = 0;

    float cst[4][4] = {{0.f,0.f,0.f,0.f},{0.f,0.f,0.f,0.f},
                       {0.f,0.f,0.f,0.f},{0.f,0.f,0.f,0.f}};

    const uint32_t* cptr[4];
    #pragma unroll
    for (int j = 0; j < 4; ++j) {
        cptr[j] = ciog + ((size_t)(b0 + kg * 4 + j) * NT1) * NU + n0 + r16;
    }

    const int amask = (r16 & 7) << 4;       // XOR swizzle on byte bits 4-6
    const int arow  = r16 * 1024;
    const int acol  = kg * 16;

    __syncthreads();

    for (int t = 0; t < NT1; ++t) {
        const int rb = t & 1;

        // prefetch ci/og for this step (consumed after MFMA phase)
        uint32_t pk[4][4];
        #pragma unroll
        for (int nf = 0; nf < 4; ++nf) {
            #pragma unroll
            for (int j = 0; j < 4; ++j) pk[nf][j] = cptr[j][nf * 16];
        }

        // previous step's output row (wave 0 only; ysum is double-buffered)
        if (t > 0 && wv == 0 && lane < NBW) {
            float y = blin;
            #pragma unroll
            for (int w8 = 0; w8 < 8; ++w8) y += ysum[(t - 1) & 1][w8][lane];
            out[(size_t)(b0 + lane) * NT1 + (t - 1)] = y;
        }

        // ---- z = h @ W_ig : 16 kf x 4 nf MFMAs ----
        f32x4 acc[4];
        #pragma unroll
        for (int nf = 0; nf < 4; ++nf) { acc[nf][0]=0.f; acc[nf][1]=0.f; acc[nf][2]=0.f; acc[nf][3]=0.f; }

        const char* hb = (const char*)hsh[rb];
        #pragma unroll
        for (int kf = 0; kf < 16; ++kf) {
            const int abyte = arow + ((kf * 64 + acol) ^ amask);
            short8_t a = *(const short8_t*)(hb + abyte);
            #pragma unroll
            for (int nf = 0; nf < 4; ++nf) {
                acc[nf] = __builtin_amdgcn_mfma_f32_16x16x32_bf16(a, wfrag[kf][nf], acc[nf], 0, 0, 0);
            }
        }

        // ---- gate math + state update + h write (to other buffer) ----
        char* hw = (char*)hsh[rb ^ 1];
        float yp[4] = {0.f, 0.f, 0.f, 0.f};
        #pragma unroll
        for (int nf = 0; nf < 4; ++nf) {
            const int u2 = (n0 + nf * 16 + r16) * 2;
            #pragma unroll
            for (int j = 0; j < 4; ++j) {
                const int b = kg * 4 + j;
                const float z   = acc[nf][j] + big[nf];
                const float igv = sigf(z);
                const uint32_t p = pk[nf][j];
                cst[nf][j] = fmaf(f_from_lo(p), igv, cst[nf][j]);
                const float hv = cst[nf][j] * f_from_hi(p);
                yp[j] = fmaf(hv, wl[nf], yp[j]);
                const int wb = b * 1024 + (u2 ^ ((b & 7) << 4));
                *(short*)(hw + wb) = (short)(bf16_top(hv) >> 16);
            }
        }

        // reduce y over the 16 u-lanes of each k-group
        #pragma unroll
        for (int m = 1; m <= 8; m <<= 1) {
            yp[0] += __shfl_xor(yp[0], m);
            yp[1] += __shfl_xor(yp[1], m);
            yp[2] += __shfl_xor(yp[2], m);
            yp[3] += __shfl_xor(yp[3], m);
        }
        if (r16 == 0) {
            #pragma unroll
            for (int j = 0; j < 4; ++j) ysum[rb][wv][kg * 4 + j] = yp[j];
        }

        #pragma unroll
        for (int j = 0; j < 4; ++j) cptr[j] += NU;

        __syncthreads();
    }

    // final output row (t = NT1-1 = 512, ysum buffer (512)&1 = 0)
    if (wv == 0 && lane < NBW) {
        float y = blin;
        #pragma unroll
        for (int w8 = 0; w8 < 8; ++w8) y += ysum[0][w8][lane];
        out[(size_t)(b0 + lane) * NT1 + NT] = y;
    }
}

// ---------------------------------------------------------------------------
// Fallback (no-ws path): validated round-1 kernel, recomputes gates in-loop.
// ---------------------------------------------------------------------------
__device__ __forceinline__ void fma4(float4& acc, const float4 w, const float s) {
    acc.x = fmaf(w.x, s, acc.x);
    acc.y = fmaf(w.y, s, acc.y);
    acc.z = fmaf(w.z, s, acc.z);
    acc.w = fmaf(w.w, s, acc.w);
}

__global__ __launch_bounds__(512) void rec_fallback(
    const float* __restrict__ states, const int* __restrict__ actions,
    const float* __restrict__ W_ci, const float* __restrict__ b_ci,
    const float* __restrict__ W_ig, const float* __restrict__ b_ig,
    const float* __restrict__ W_og, const float* __restrict__ b_og,
    const float* __restrict__ W_lin, const float* __restrict__ b_lin,
    float* __restrict__ out)
{
    __shared__ __align__(16) float h_lds[2][NU];
    __shared__ __align__(16) float part[4][2][NU];
    __shared__ float ysum[8][2];
    __shared__ float x_lds[2][NS];
    __shared__ int a_lds[2];

    const int tid = threadIdx.x;
    const int b0 = blockIdx.x * 2;
    const int uq = tid & 127;
    const int kq = tid >> 7;
    const int k0 = kq << 7;

    h_lds[0][tid] = 0.0f;
    h_lds[1][tid] = 0.0f;
    float c0 = 0.0f, c1 = 0.0f;
    const float wlin = W_lin[tid];
    const float big_ = b_ig[tid];
    const float blin = b_lin[0];
    const float bc = b_ci[tid], bo = b_og[tid];
    __syncthreads();

    for (int t = 0; t < NT1; ++t) {
        if (tid < 128) {
            const int bb = tid >> 6, i = tid & 63;
            x_lds[bb][i] = states[((size_t)(b0 + bb) * NT1 + t) * NS + i];
        } else if (tid < 130) {
            const int bb = tid - 128;
            a_lds[bb] = (t < NT) ? actions[(b0 + bb) * NT + t] : -1;
        }

        float4 a0 = make_float4(0.f, 0.f, 0.f, 0.f);
        float4 a1 = make_float4(0.f, 0.f, 0.f, 0.f);
        for (int kk = 0; kk < 128; kk += 4) {
            const int k = k0 + kk;
            const float4 h0v = *(const float4*)&h_lds[0][k];
            const float4 h1v = *(const float4*)&h_lds[1][k];
            const float* wr = W_ig + (size_t)k * NU + (uq << 2);
            const float4 w0 = *(const float4*)(wr);
            const float4 w1 = *(const float4*)(wr + NU);
            const float4 w2 = *(const float4*)(wr + 2 * NU);
            const float4 w3 = *(const float4*)(wr + 3 * NU);
            fma4(a0, w0, h0v.x); fma4(a1, w0, h1v.x);
            fma4(a0, w1, h0v.y); fma4(a1, w1, h1v.y);
            fma4(a0, w2, h0v.z); fma4(a1, w2, h1v.z);
            fma4(a0, w3, h0v.w); fma4(a1, w3, h1v.w);
        }
        *(float4*)&part[kq][0][uq << 2] = a0;
        *(float4*)&part[kq][1][uq << 2] = a1;
        __syncthreads();

        float z0 = big_, z1 = big_;
        #pragma unroll
        for (int q = 0; q < 4; ++q) { z0 += part[q][0][tid]; z1 += part[q][1][tid]; }

        float zc0 = bc, zo0 = bo, zc1 = bc, zo1 = bo;
        for (int i = 0; i < NS; ++i) {
            const float wc = W_ci[(size_t)i * NU + tid];
            const float wo = W_og[(size_t)i * NU + tid];
            const float s0v = x_lds[0][i];
            const float s1v = x_lds[1][i];
            zc0 = fmaf(s0v, wc, zc0); zo0 = fmaf(s0v, wo, zo0);
            zc1 = fmaf(s1v, wc, zc1); zo1 = fmaf(s1v, wo, zo1);
        }
        const int a0i = a_lds[0], a1i = a_lds[1];
        if (a0i >= 0) { zc0 += W_ci[(size_t)(NS + a0i) * NU + tid]; zo0 += W_og[(size_t)(NS + a0i) * NU + tid]; }
        if (a1i >= 0) { zc1 += W_ci[(size_t)(NS + a1i) * NU + tid]; zo1 += W_og[(size_t)(NS + a1i) * NU + tid]; }
        const float ci0 = tanh_fast(zc0), og0 = sigf(zo0);
        const float ci1 = tanh_fast(zc1), og1 = sigf(zo1);

        const float ig0 = sigf(z0), ig1 = sigf(z1);
        c0 = fmaf(ci0, ig0, c0);
        c1 = fmaf(ci1, ig1, c1);
        const float h0 = c0 * og0, h1 = c1 * og1;
        h_lds[0][tid] = h0;
        h_lds[1][tid] = h1;

        float y0 = h0 * wlin, y1 = h1 * wlin;
        #pragma unroll
        for (int off = 32; off > 0; off >>= 1) {
            y0 += __shfl_xor(y0, off);
            y1 += __shfl_xor(y1, off);
        }
        if ((tid & 63) == 0) { ysum[tid >> 6][0] = y0; ysum[tid >> 6][1] = y1; }
        __syncthreads();

        if (tid < 2) {
            float y = blin;
            #pragma unroll
            for (int w = 0; w < 8; ++w) y += ysum[w][tid];
            out[(size_t)(b0 + tid) * NT1 + t] = y;
        }
    }
}

extern "C" void kernel_launch(void* const* d_in, const int* in_sizes, int n_in,
                              void* d_out, int out_size, void* d_ws, size_t ws_size,
                              hipStream_t stream) {
    const float* states = (const float*)d_in[0];
    const int*   actions= (const int*)d_in[1];
    const float* W_ci = (const float*)d_in[2];
    const float* b_ci = (const float*)d_in[3];
    const float* W_ig = (const float*)d_in[4];
    const float* b_ig = (const float*)d_in[5];
    const float* W_og = (const float*)d_in[6];
    const float* b_og = (const float*)d_in[7];
    const float* W_lin= (const float*)d_in[8];
    const float* b_lin= (const float*)d_in[9];
    float* out = (float*)d_out;

    const size_t need = (size_t)NBATCH * NT1 * NU * sizeof(uint32_t);  // 134.5 MB
    if (ws_size >= need) {
        uint32_t* ciog = (uint32_t*)d_ws;
        ff_kernel<<<dim3(NBATCH * 17), dim3(512), 0, stream>>>(
            states, actions, W_ci, b_ci, W_og, b_og, ciog);
        rec_mfma<<<dim3(NBATCH / NBW), dim3(512), 0, stream>>>(
            W_ig, b_ig, W_lin, b_lin, ciog, out);
    } else {
        rec_fallback<<<dim3(NBATCH / 2), dim3(512), 0, stream>>>(
            states, actions, W_ci, b_ci, W_ig, b_ig, W_og, b_og, W_lin, b_lin, out);
    }
}

// Round 3
// 3617.959 us; speedup vs baseline: 1.4135x; 1.4135x over previous
//
#include <hip/hip_runtime.h>
#include <cstdint>

#define NBATCH 128
#define NT 512
#define NT1 513
#define NS 64
#define NU 512
#define NBW 16          // batches per workgroup
#define KF_REG 8        // k-fragments (of 16) resident in VGPRs
#define KF_LDS 4        // k-fragments resident in LDS
#define KF_STR 4        // k-fragments streamed from L2 each step
#define KF_SHORTS (8 * 4 * 64 * 8)          // shorts per kf across a WG = 16384
#define PACK_SHORTS (16 * KF_SHORTS)        // 262144 shorts = 512KB
#define CIOG_BYTES ((size_t)NBATCH * NT1 * NU * 4)   // 134,479,872
#define DYN_LDS (KF_LDS * KF_SHORTS * 2)    // 131072 B

typedef __attribute__((ext_vector_type(8))) short short8_t;
typedef __attribute__((ext_vector_type(4))) float f32x4;

__device__ __forceinline__ float sigf(float z) {
    return 1.0f / (1.0f + __expf(-z));
}
__device__ __forceinline__ float tanh_fast(float z) {
    return 2.0f / (1.0f + __expf(-2.0f * z)) - 1.0f;
}
__device__ __forceinline__ uint32_t bf16_top(float f) {   // RNE, result in top 16
    uint32_t u = __float_as_uint(f);
    u += 0x7FFFu + ((u >> 16) & 1u);
    return u & 0xFFFF0000u;
}
__device__ __forceinline__ float f_from_lo(uint32_t p) { return __uint_as_float(p << 16); }
__device__ __forceinline__ float f_from_hi(uint32_t p) { return __uint_as_float(p & 0xFFFF0000u); }

// ---------------------------------------------------------------------------
// pack_kernel: one-time reorder of W_ig (f32 [k][u]) into bf16 MFMA-fragment
// order: pack[kf][wv][nf][lane][j], so rec-kernel W loads are linear dwordx4.
// value = bf16(W_ig[(kf*32 + (lane>>4)*8 + j) * 512 + wv*64 + nf*16 + (lane&15)])
// ---------------------------------------------------------------------------
__global__ __launch_bounds__(512) void pack_kernel(
    const float* __restrict__ W_ig, short* __restrict__ pack)
{
    const int g = blockIdx.x * 512 + threadIdx.x;   // 32768 threads
    const int lane = g & 63;
    const int nf = (g >> 6) & 3;
    const int wv = (g >> 8) & 7;
    const int kf = g >> 11;
    const int r16 = lane & 15, kg = lane >> 4;
    const int u = wv * 64 + nf * 16 + r16;
    const int kb = kf * 32 + kg * 8;
    short8_t w;
    #pragma unroll
    for (int j = 0; j < 8; ++j) {
        w[j] = (short)(bf16_top(W_ig[(size_t)(kb + j) * NU + u]) >> 16);
    }
    *(short8_t*)(pack + (size_t)g * 8) = w;
}

// ---------------------------------------------------------------------------
// ff_kernel: feedforward gates for all (b,t) -> packed bf16 (ci lo, og hi).
// (unchanged, validated rounds 1-2)
// ---------------------------------------------------------------------------
__global__ __launch_bounds__(512) void ff_kernel(
    const float* __restrict__ states, const int* __restrict__ actions,
    const float* __restrict__ W_ci, const float* __restrict__ b_ci,
    const float* __restrict__ W_og, const float* __restrict__ b_og,
    uint32_t* __restrict__ ciog)
{
    __shared__ __align__(16) float sh_s[32][64];
    __shared__ int sh_a[32];
    const int tid = threadIdx.x;
    const int b = blockIdx.x / 17;
    const int t0 = (blockIdx.x % 17) * 32;
    const int tcnt = (t0 + 32 <= NT1) ? 32 : (NT1 - t0);

    const float* sp = states + ((size_t)b * NT1 + t0) * NS;
    for (int j = tid; j < tcnt * 16; j += 512) {
        const float4 v = *(const float4*)(sp + j * 4);
        *(float4*)&sh_s[j >> 4][(j & 15) * 4] = v;
    }
    for (int tt = tid; tt < tcnt; tt += 512) {
        const int t = t0 + tt;
        sh_a[tt] = (t < NT) ? actions[b * NT + t] : -1;
    }
    __syncthreads();

    const int u = tid;
    float accc[32], acco[32];
    const float bc = b_ci[u], bo = b_og[u];
    #pragma unroll
    for (int tt = 0; tt < 32; ++tt) { accc[tt] = bc; acco[tt] = bo; }

    for (int i = 0; i < NS; ++i) {
        const float wc = W_ci[(size_t)i * NU + u];
        const float wo = W_og[(size_t)i * NU + u];
        #pragma unroll
        for (int tt = 0; tt < 32; ++tt) {
            const float s = sh_s[tt][i];
            accc[tt] = fmaf(s, wc, accc[tt]);
            acco[tt] = fmaf(s, wo, acco[tt]);
        }
    }
    #pragma unroll
    for (int tt = 0; tt < 32; ++tt) {
        if (tt < tcnt) {
            float zc = accc[tt], zo = acco[tt];
            const int a = sh_a[tt];
            if (a >= 0) {
                zc += W_ci[(size_t)(NS + a) * NU + u];
                zo += W_og[(size_t)(NS + a) * NU + u];
            }
            const float ci = tanh_fast(zc);
            const float og = sigf(zo);
            ciog[((size_t)b * NT1 + t0 + tt) * NU + u] = bf16_top(og) | (bf16_top(ci) >> 16);
        }
    }
}

// ---------------------------------------------------------------------------
// rec_mfma2: recurrence with W split reg(8kf) / LDS(4kf) / L2-stream(4kf).
// 8 WGs x 512 thr, WG owns 16 batches, wave wv owns u-slice [wv*64, +64).
// Single h buffer (16KB static) + 128KB dynamic LDS for W. 2 barriers/step.
// Stream frags double-buffer rotated (wsA/wsB) and interleaved with the
// reg/LDS MFMA clusters to hide L2 latency.
// ---------------------------------------------------------------------------
__global__ __launch_bounds__(512, 2) void rec_mfma2(
    const short* __restrict__ pack,
    const float* __restrict__ b_ig, const float* __restrict__ W_lin,
    const float* __restrict__ b_lin,
    const uint32_t* __restrict__ ciog, float* __restrict__ out)
{
    extern __shared__ __align__(16) char dynsm[];      // 128KB W-LDS
    __shared__ __align__(16) short hsh[NBW * NU];      // 16KB, single buffer
    __shared__ float ysum[2][8][NBW];

    const int tid  = threadIdx.x;
    const int lane = tid & 63;
    const int wv   = tid >> 6;
    const int n0   = wv << 6;
    const int r16  = lane & 15;
    const int kg   = lane >> 4;
    const int b0   = blockIdx.x * NBW;

    // ---- one-time: 8 kf of W into VGPRs (128 regs) ----
    const short8_t* pr = (const short8_t*)pack;
    short8_t wreg[KF_REG][4];
    #pragma unroll
    for (int kf = 0; kf < KF_REG; ++kf) {
        #pragma unroll
        for (int nf = 0; nf < 4; ++nf) {
            wreg[kf][nf] = pr[((kf * 8 + wv) * 4 + nf) * 64 + lane];
        }
    }

    // ---- one-time: 4 kf of W into LDS (linear copy, layout == pack) ----
    const short8_t* pl = (const short8_t*)(pack + KF_REG * KF_SHORTS);
    short8_t* dl = (short8_t*)dynsm;
    #pragma unroll
    for (int i = 0; i < 16; ++i) {
        const int idx = i * 512 + tid;
        dl[idx] = pl[idx];
    }
    // stream region base (4 kf)
    const short8_t* strp = (const short8_t*)(pack + (KF_REG + KF_LDS) * KF_SHORTS);

    float big[4], wl[4];
    #pragma unroll
    for (int nf = 0; nf < 4; ++nf) {
        big[nf] = b_ig[n0 + nf * 16 + r16];
        wl[nf]  = W_lin[n0 + nf * 16 + r16];
    }
    const float blin = b_lin[0];

    for (int i = tid; i < NBW * NU; i += 512) hsh[i] = 0;

    float cst[4][4] = {{0.f,0.f,0.f,0.f},{0.f,0.f,0.f,0.f},
                       {0.f,0.f,0.f,0.f},{0.f,0.f,0.f,0.f}};

    const uint32_t* cptr[4];
    #pragma unroll
    for (int j = 0; j < 4; ++j) {
        cptr[j] = ciog + ((size_t)(b0 + kg * 4 + j) * NT1) * NU + n0 + r16;
    }

    const int amask = (r16 & 7) << 4;    // XOR swizzle (validated round 2)
    const char* hb = (const char*)hsh;
    char* hw = (char*)hsh;

    __syncthreads();

    for (int t = 0; t < NT1; ++t) {
        // stream buffers: kf12 -> wsA, kf13 -> wsB (issued at loop top)
        short8_t wsA[4], wsB[4];
        #pragma unroll
        for (int nf = 0; nf < 4; ++nf) wsA[nf] = strp[((0 * 8 + wv) * 4 + nf) * 64 + lane];
        #pragma unroll
        for (int nf = 0; nf < 4; ++nf) wsB[nf] = strp[((1 * 8 + wv) * 4 + nf) * 64 + lane];

        // ci/og for this step (consumed after barrier 1)
        uint32_t pk[4][4];
        #pragma unroll
        for (int nf = 0; nf < 4; ++nf) {
            #pragma unroll
            for (int j = 0; j < 4; ++j) pk[nf][j] = cptr[j][nf * 16];
        }

        // previous step's output row (ysum double-buffered)
        if (t > 0 && wv == 0 && lane < NBW) {
            float y = blin;
            #pragma unroll
            for (int w8 = 0; w8 < 8; ++w8) y += ysum[(t - 1) & 1][w8][lane];
            out[(size_t)(b0 + lane) * NT1 + (t - 1)] = y;
        }

        f32x4 acc[4];
        #pragma unroll
        for (int nf = 0; nf < 4; ++nf) { acc[nf][0]=0.f; acc[nf][1]=0.f; acc[nf][2]=0.f; acc[nf][3]=0.f; }

        #define AFRAG(KF) (*(const short8_t*)(hb + r16 * 1024 + ((((KF) * 64) + kg * 16) ^ amask)))

        // ---- reg kf 0..5 ----
        #pragma unroll
        for (int kf = 0; kf < 6; ++kf) {
            const short8_t a = AFRAG(kf);
            #pragma unroll
            for (int nf = 0; nf < 4; ++nf)
                acc[nf] = __builtin_amdgcn_mfma_f32_16x16x32_bf16(a, wreg[kf][nf], acc[nf], 0, 0, 0);
        }
        // ---- stream kf12 (wsA), then reload wsA <- kf14 ----
        {
            const short8_t a = AFRAG(12);
            #pragma unroll
            for (int nf = 0; nf < 4; ++nf)
                acc[nf] = __builtin_amdgcn_mfma_f32_16x16x32_bf16(a, wsA[nf], acc[nf], 0, 0, 0);
        }
        #pragma unroll
        for (int nf = 0; nf < 4; ++nf) wsA[nf] = strp[((2 * 8 + wv) * 4 + nf) * 64 + lane];
        // ---- stream kf13 (wsB), then reload wsB <- kf15 ----
        {
            const short8_t a = AFRAG(13);
            #pragma unroll
            for (int nf = 0; nf < 4; ++nf)
                acc[nf] = __builtin_amdgcn_mfma_f32_16x16x32_bf16(a, wsB[nf], acc[nf], 0, 0, 0);
        }
        #pragma unroll
        for (int nf = 0; nf < 4; ++nf) wsB[nf] = strp[((3 * 8 + wv) * 4 + nf) * 64 + lane];

        // ---- reg kf 6..7 ----
        #pragma unroll
        for (int kf = 6; kf < 8; ++kf) {
            const short8_t a = AFRAG(kf);
            #pragma unroll
            for (int nf = 0; nf < 4; ++nf)
                acc[nf] = __builtin_amdgcn_mfma_f32_16x16x32_bf16(a, wreg[kf][nf], acc[nf], 0, 0, 0);
        }
        // ---- LDS kf 8..11 ----
        #pragma unroll
        for (int kf = 0; kf < KF_LDS; ++kf) {
            const short8_t a = AFRAG(8 + kf);
            #pragma unroll
            for (int nf = 0; nf < 4; ++nf) {
                const short8_t w = dl[((kf * 8 + wv) * 4 + nf) * 64 + lane];
                acc[nf] = __builtin_amdgcn_mfma_f32_16x16x32_bf16(a, w, acc[nf], 0, 0, 0);
            }
        }
        // ---- stream kf14 (wsA), kf15 (wsB) ----
        {
            const short8_t a = AFRAG(14);
            #pragma unroll
            for (int nf = 0; nf < 4; ++nf)
                acc[nf] = __builtin_amdgcn_mfma_f32_16x16x32_bf16(a, wsA[nf], acc[nf], 0, 0, 0);
        }
        {
            const short8_t a = AFRAG(15);
            #pragma unroll
            for (int nf = 0; nf < 4; ++nf)
                acc[nf] = __builtin_amdgcn_mfma_f32_16x16x32_bf16(a, wsB[nf], acc[nf], 0, 0, 0);
        }
        #undef AFRAG

        __syncthreads();   // barrier 1: all h reads done

        // ---- gate math + state update + h write (same buffer, now safe) ----
        float yp[4] = {0.f, 0.f, 0.f, 0.f};
        #pragma unroll
        for (int nf = 0; nf < 4; ++nf) {
            const int u2 = (n0 + nf * 16 + r16) * 2;
            #pragma unroll
            for (int j = 0; j < 4; ++j) {
                const int b = kg * 4 + j;
                const float z   = acc[nf][j] + big[nf];
                const float igv = sigf(z);
                const uint32_t p = pk[nf][j];
                cst[nf][j] = fmaf(f_from_lo(p), igv, cst[nf][j]);
                const float hv = cst[nf][j] * f_from_hi(p);
                yp[j] = fmaf(hv, wl[nf], yp[j]);
                const int wb = b * 1024 + (u2 ^ ((b & 7) << 4));
                *(short*)(hw + wb) = (short)(bf16_top(hv) >> 16);
            }
        }

        #pragma unroll
        for (int m = 1; m <= 8; m <<= 1) {
            yp[0] += __shfl_xor(yp[0], m);
            yp[1] += __shfl_xor(yp[1], m);
            yp[2] += __shfl_xor(yp[2], m);
            yp[3] += __shfl_xor(yp[3], m);
        }
        if (r16 == 0) {
            #pragma unroll
            for (int j = 0; j < 4; ++j) ysum[t & 1][wv][kg * 4 + j] = yp[j];
        }

        #pragma unroll
        for (int j = 0; j < 4; ++j) cptr[j] += NU;

        __syncthreads();   // barrier 2: h_{t+1} visible
    }

    if (wv == 0 && lane < NBW) {
        float y = blin;
        #pragma unroll
        for (int w8 = 0; w8 < 8; ++w8) y += ysum[0][w8][lane];
        out[(size_t)(b0 + lane) * NT1 + NT] = y;
    }
}

// ---------------------------------------------------------------------------
// Fallback (ws too small): validated round-1 kernel.
// ---------------------------------------------------------------------------
__device__ __forceinline__ void fma4(float4& acc, const float4 w, const float s) {
    acc.x = fmaf(w.x, s, acc.x);
    acc.y = fmaf(w.y, s, acc.y);
    acc.z = fmaf(w.z, s, acc.z);
    acc.w = fmaf(w.w, s, acc.w);
}

__global__ __launch_bounds__(512) void rec_fallback(
    const float* __restrict__ states, const int* __restrict__ actions,
    const float* __restrict__ W_ci, const float* __restrict__ b_ci,
    const float* __restrict__ W_ig, const float* __restrict__ b_ig,
    const float* __restrict__ W_og, const float* __restrict__ b_og,
    const float* __restrict__ W_lin, const float* __restrict__ b_lin,
    float* __restrict__ out)
{
    __shared__ __align__(16) float h_lds[2][NU];
    __shared__ __align__(16) float part[4][2][NU];
    __shared__ float ysum[8][2];
    __shared__ float x_lds[2][NS];
    __shared__ int a_lds[2];

    const int tid = threadIdx.x;
    const int b0 = blockIdx.x * 2;
    const int uq = tid & 127;
    const int kq = tid >> 7;
    const int k0 = kq << 7;

    h_lds[0][tid] = 0.0f;
    h_lds[1][tid] = 0.0f;
    float c0 = 0.0f, c1 = 0.0f;
    const float wlin = W_lin[tid];
    const float big_ = b_ig[tid];
    const float blin = b_lin[0];
    const float bc = b_ci[tid], bo = b_og[tid];
    __syncthreads();

    for (int t = 0; t < NT1; ++t) {
        if (tid < 128) {
            const int bb = tid >> 6, i = tid & 63;
            x_lds[bb][i] = states[((size_t)(b0 + bb) * NT1 + t) * NS + i];
        } else if (tid < 130) {
            const int bb = tid - 128;
            a_lds[bb] = (t < NT) ? actions[(b0 + bb) * NT + t] : -1;
        }

        float4 a0 = make_float4(0.f, 0.f, 0.f, 0.f);
        float4 a1 = make_float4(0.f, 0.f, 0.f, 0.f);
        for (int kk = 0; kk < 128; kk += 4) {
            const int k = k0 + kk;
            const float4 h0v = *(const float4*)&h_lds[0][k];
            const float4 h1v = *(const float4*)&h_lds[1][k];
            const float* wr = W_ig + (size_t)k * NU + (uq << 2);
            const float4 w0 = *(const float4*)(wr);
            const float4 w1 = *(const float4*)(wr + NU);
            const float4 w2 = *(const float4*)(wr + 2 * NU);
            const float4 w3 = *(const float4*)(wr + 3 * NU);
            fma4(a0, w0, h0v.x); fma4(a1, w0, h1v.x);
            fma4(a0, w1, h0v.y); fma4(a1, w1, h1v.y);
            fma4(a0, w2, h0v.z); fma4(a1, w2, h1v.z);
            fma4(a0, w3, h0v.w); fma4(a1, w3, h1v.w);
        }
        *(float4*)&part[kq][0][uq << 2] = a0;
        *(float4*)&part[kq][1][uq << 2] = a1;
        __syncthreads();

        float z0 = big_, z1 = big_;
        #pragma unroll
        for (int q = 0; q < 4; ++q) { z0 += part[q][0][tid]; z1 += part[q][1][tid]; }

        float zc0 = bc, zo0 = bo, zc1 = bc, zo1 = bo;
        for (int i = 0; i < NS; ++i) {
            const float wc = W_ci[(size_t)i * NU + tid];
            const float wo = W_og[(size_t)i * NU + tid];
            const float s0v = x_lds[0][i];
            const float s1v = x_lds[1][i];
            zc0 = fmaf(s0v, wc, zc0); zo0 = fmaf(s0v, wo, zo0);
            zc1 = fmaf(s1v, wc, zc1); zo1 = fmaf(s1v, wo, zo1);
        }
        const int a0i = a_lds[0], a1i = a_lds[1];
        if (a0i >= 0) { zc0 += W_ci[(size_t)(NS + a0i) * NU + tid]; zo0 += W_og[(size_t)(NS + a0i) * NU + tid]; }
        if (a1i >= 0) { zc1 += W_ci[(size_t)(NS + a1i) * NU + tid]; zo1 += W_og[(size_t)(NS + a1i) * NU + tid]; }
        const float ci0 = tanh_fast(zc0), og0 = sigf(zo0);
        const float ci1 = tanh_fast(zc1), og1 = sigf(zo1);

        const float ig0 = sigf(z0), ig1 = sigf(z1);
        c0 = fmaf(ci0, ig0, c0);
        c1 = fmaf(ci1, ig1, c1);
        const float h0 = c0 * og0, h1 = c1 * og1;
        h_lds[0][tid] = h0;
        h_lds[1][tid] = h1;

        float y0 = h0 * wlin, y1 = h1 * wlin;
        #pragma unroll
        for (int off = 32; off > 0; off >>= 1) {
            y0 += __shfl_xor(y0, off);
            y1 += __shfl_xor(y1, off);
        }
        if ((tid & 63) == 0) { ysum[tid >> 6][0] = y0; ysum[tid >> 6][1] = y1; }
        __syncthreads();

        if (tid < 2) {
            float y = blin;
            #pragma unroll
            for (int w = 0; w < 8; ++w) y += ysum[w][tid];
            out[(size_t)(b0 + tid) * NT1 + t] = y;
        }
    }
}

extern "C" void kernel_launch(void* const* d_in, const int* in_sizes, int n_in,
                              void* d_out, int out_size, void* d_ws, size_t ws_size,
                              hipStream_t stream) {
    const float* states = (const float*)d_in[0];
    const int*   actions= (const int*)d_in[1];
    const float* W_ci = (const float*)d_in[2];
    const float* b_ci = (const float*)d_in[3];
    const float* W_ig = (const float*)d_in[4];
    const float* b_ig = (const float*)d_in[5];
    const float* W_og = (const float*)d_in[6];
    const float* b_og = (const float*)d_in[7];
    const float* W_lin= (const float*)d_in[8];
    const float* b_lin= (const float*)d_in[9];
    float* out = (float*)d_out;

    const size_t need = CIOG_BYTES + (size_t)PACK_SHORTS * 2;   // ~135 MB
    if (ws_size >= need) {
        uint32_t* ciog = (uint32_t*)d_ws;
        short* pack = (short*)((char*)d_ws + CIOG_BYTES);

        (void)hipFuncSetAttribute((const void*)rec_mfma2,
                                  hipFuncAttributeMaxDynamicSharedMemorySize, DYN_LDS);

        pack_kernel<<<dim3(64), dim3(512), 0, stream>>>(W_ig, pack);
        ff_kernel<<<dim3(NBATCH * 17), dim3(512), 0, stream>>>(
            states, actions, W_ci, b_ci, W_og, b_og, ciog);
        rec_mfma2<<<dim3(NBATCH / NBW), dim3(512), DYN_LDS, stream>>>(
            pack, b_ig, W_lin, b_lin, ciog, out);
    } else {
        rec_fallback<<<dim3(NBATCH / 2), dim3(512), 0, stream>>>(
            states, actions, W_ci, b_ci, W_ig, b_ig, W_og, b_og, W_lin, b_lin, out);
    }
}